// Round 6
// baseline (560.744 us; speedup 1.0000x reference)
//
#include <hip/hip_runtime.h>
#include <cstddef>
#include <cmath>

// Problem constants
#define NROWS 16384   // 32*512
#define DIM   512
#define KC    2048

// d_out layout (float32 element offsets)
#define Q_OFF    0ul
#define LOSS_OFF 8388608ul    // 33,554,432 elems (reused as sim scratch)
#define NN_OFF   41943040ul   // 16,384 elems
#define CB_OFF   41959424ul   // 1,048,576 elems
#define CNT_OFF  43008000ul   // 2,048 elems

#define FLAG_CAP 4096
#define FLAG_TAU 3e-5f        // 3-term split: argmax errors ~1e-6; 3e-5 proven r1-r3/r5

// ws layout (32-bit slots)
#define WS_LOSS   0
#define WS_CNT    4       // 2048 ints
#define WS_DIV    2052    // 2048 floats (fp32-atomic diversity column sums)
#define WS_ENT    4100    // 1024 floats (per-block entropy partials)
#define WS_NFLAG  5124
#define WS_FLAGS  5128    // 3*4096 ints
#define WS_ZEND   5128    // zero range [0, WS_ZEND)

typedef __attribute__((ext_vector_type(8))) short short8;
typedef __attribute__((ext_vector_type(4))) float f32x4;

// ----------------------------------------------------------- bf16 split -----
__device__ __forceinline__ short hi1(float f) {
    return (short)(__float_as_uint(f) >> 16);
}
__device__ __forceinline__ short lo1(float f) {
    unsigned int u = __float_as_uint(f);
    float l = f - __uint_as_float(u & 0xffff0000u);
    return (short)(__float_as_uint(l) >> 16);
}
__device__ __forceinline__ short8 hi8(float4 a, float4 b) {
    short8 r;
    r[0]=hi1(a.x); r[1]=hi1(a.y); r[2]=hi1(a.z); r[3]=hi1(a.w);
    r[4]=hi1(b.x); r[5]=hi1(b.y); r[6]=hi1(b.z); r[7]=hi1(b.w);
    return r;
}
__device__ __forceinline__ short8 lo8(float4 a, float4 b) {
    short8 r;
    r[0]=lo1(a.x); r[1]=lo1(a.y); r[2]=lo1(a.z); r[3]=lo1(a.w);
    r[4]=lo1(b.x); r[5]=lo1(b.y); r[6]=lo1(b.z); r[7]=lo1(b.w);
    return r;
}

// ---------------------------------------------------------------- GEMM ------
// sim = A x B^T via bf16 hi/lo 3-term split: Ah*Bh + Al*Bh + Ah*Bl. (known-good)
#define LDW  40
#define AH_B 0
#define AL_B 5120
#define BH_B 10240
#define BL_B 15360

__global__ __launch_bounds__(256, 3) void gemm_mfma(const float* __restrict__ A,
                                                    const float* __restrict__ B,
                                                    float* __restrict__ C,
                                                    int* __restrict__ ws) {
    if (blockIdx.x == 0 && blockIdx.y == 0) {
        for (int i = threadIdx.x; i < WS_ZEND; i += 256) ws[i] = 0;
    }
    __shared__ ushort smem[20480];   // 40 KB
    const int t    = threadIdx.x;
    const int n0   = blockIdx.x * 128;
    const int m0   = blockIdx.y * 128;
    const int rsub = t >> 2;
    const int kc   = (t & 3) * 8;
    const int lane = t & 63, quad = lane >> 4, lr = lane & 15;
    const int w = t >> 6, wm = w >> 1, wn = w & 1;

    f32x4 acc[4][4] = {};

    const float* Abase = A + (size_t)(m0 + rsub) * DIM + kc;
    const float* Bbase = B + (size_t)(n0 + rsub) * DIM + kc;

    float4 pa0 = *(const float4*)(Abase);
    float4 pa1 = *(const float4*)(Abase + 4);
    float4 pa2 = *(const float4*)(Abase + 64 * DIM);
    float4 pa3 = *(const float4*)(Abase + 64 * DIM + 4);
    float4 pb0 = *(const float4*)(Bbase);
    float4 pb1 = *(const float4*)(Bbase + 4);
    float4 pb2 = *(const float4*)(Bbase + 64 * DIM);
    float4 pb3 = *(const float4*)(Bbase + 64 * DIM + 4);

    ushort* wa0 = smem + AH_B + rsub * LDW + kc;
    ushort* wa1 = smem + AH_B + (rsub + 64) * LDW + kc;
    ushort* wb0 = smem + BH_B + rsub * LDW + kc;
    ushort* wb1 = smem + BH_B + (rsub + 64) * LDW + kc;

    const ushort* ra = smem + (wm * 64 + lr) * LDW + quad * 8;
    const ushort* rb = smem + (wn * 64 + lr) * LDW + quad * 8;

    for (int kk = 0; kk < 16; ++kk) {
        *(short8*)(wa0)        = hi8(pa0, pa1);
        *(short8*)(wa0 + AL_B) = lo8(pa0, pa1);
        *(short8*)(wa1)        = hi8(pa2, pa3);
        *(short8*)(wa1 + AL_B) = lo8(pa2, pa3);
        *(short8*)(wb0)        = hi8(pb0, pb1);
        *(short8*)(wb0 + AL_B) = lo8(pb0, pb1);
        *(short8*)(wb1)        = hi8(pb2, pb3);
        *(short8*)(wb1 + AL_B) = lo8(pb2, pb3);
        __syncthreads();

        if (kk < 15) {
            const float* a = Abase + (kk + 1) * 32;
            const float* b = Bbase + (kk + 1) * 32;
            pa0 = *(const float4*)(a);
            pa1 = *(const float4*)(a + 4);
            pa2 = *(const float4*)(a + 64 * DIM);
            pa3 = *(const float4*)(a + 64 * DIM + 4);
            pb0 = *(const float4*)(b);
            pb1 = *(const float4*)(b + 4);
            pb2 = *(const float4*)(b + 64 * DIM);
            pb3 = *(const float4*)(b + 64 * DIM + 4);
        }

        short8 ah[4], al[4], bx[4];
        #pragma unroll
        for (int mt = 0; mt < 4; ++mt) ah[mt] = *(const short8*)(ra + AH_B + mt * 16 * LDW);
        #pragma unroll
        for (int nt = 0; nt < 4; ++nt) bx[nt] = *(const short8*)(rb + BH_B + nt * 16 * LDW);
        #pragma unroll
        for (int mt = 0; mt < 4; ++mt)
            #pragma unroll
            for (int nt = 0; nt < 4; ++nt)
                acc[mt][nt] = __builtin_amdgcn_mfma_f32_16x16x32_bf16(ah[mt], bx[nt], acc[mt][nt], 0, 0, 0);
        #pragma unroll
        for (int mt = 0; mt < 4; ++mt) al[mt] = *(const short8*)(ra + AL_B + mt * 16 * LDW);
        #pragma unroll
        for (int mt = 0; mt < 4; ++mt)
            #pragma unroll
            for (int nt = 0; nt < 4; ++nt)
                acc[mt][nt] = __builtin_amdgcn_mfma_f32_16x16x32_bf16(al[mt], bx[nt], acc[mt][nt], 0, 0, 0);
        #pragma unroll
        for (int nt = 0; nt < 4; ++nt) bx[nt] = *(const short8*)(rb + BL_B + nt * 16 * LDW);
        #pragma unroll
        for (int mt = 0; mt < 4; ++mt)
            #pragma unroll
            for (int nt = 0; nt < 4; ++nt)
                acc[mt][nt] = __builtin_amdgcn_mfma_f32_16x16x32_bf16(ah[mt], bx[nt], acc[mt][nt], 0, 0, 0);
        __syncthreads();
    }

    #pragma unroll
    for (int mt = 0; mt < 4; ++mt) {
        #pragma unroll
        for (int nt = 0; nt < 4; ++nt) {
            const int r0 = m0 + wm * 64 + mt * 16 + quad * 4;
            const int c0 = n0 + wn * 64 + nt * 16 + lr;
            #pragma unroll
            for (int j = 0; j < 4; ++j)
                C[(size_t)(r0 + j) * KC + c0] = acc[mt][nt][j];
        }
    }
}

// ------------------------------------------------------------ block reduce --
__device__ __forceinline__ float block_reduce_sum(float v, volatile float* sf,
                                                  int lane, int w) {
    #pragma unroll
    for (int off = 32; off; off >>= 1) v += __shfl_xor(v, off, 64);
    if (lane == 0) sf[w] = v;
    __syncthreads();
    v = sf[0] + sf[1] + sf[2] + sf[3];
    __syncthreads();
    return v;
}

// ---------------------------------------------------------------- row pass --
// 2-wave teams: one row per 128 lanes (16 cols/lane), 2 rows in flight per
// block, 8 row-iterations -> 16 rows/block, grid 1024. Register-light
// (dacc[4]+e[4] float4), no launch-bounds cap. Diversity: LDS-combined then
// fp32 atomicAdd into global div[2048] (loss-path only; ~1e-5 error).
__global__ void rowpass(const float* __restrict__ sim,
                        float* __restrict__ nn,
                        float* __restrict__ div,       // ws [2048]
                        int*   __restrict__ counts,    // ws [2048]
                        float* __restrict__ entpart,   // ws [1024]
                        int*   __restrict__ nflag,
                        int*   __restrict__ flags) {
    __shared__ float divp[KC];
    __shared__ float redv[4][2];   // per wave: best val, runner val
    __shared__ int   redi[4][2];
    __shared__ float zs[4][2];     // per wave: Z, S
    __shared__ float sent[2];

    const int t    = threadIdx.x;
    const int w    = t >> 6;
    const int team = t >> 7;        // 0,1
    const int tl   = t & 127;       // team lane
    const int col0 = tl * 4;
    const int b    = blockIdx.x;
    const int w0   = team * 2, w1 = team * 2 + 1;

    float4 dacc[4] = {};
    float ent_acc = 0.f;

    #pragma unroll 1
    for (int i = 0; i < 8; ++i) {
        const int row = b * 16 + team * 8 + i;
        const float* rp = sim + (size_t)row * KC;
        float4 e[4];
        #pragma unroll
        for (int j = 0; j < 4; ++j) e[j] = *(const float4*)(rp + col0 + 512 * j);

        // ---- local top-2 over 16 values (first-occurrence ties) ----
        float bv = -3.0e38f, rv = -3.0e38f;
        int   bi = 0x7fffffff, ri = 0x7fffffff;
        #pragma unroll
        for (int j = 0; j < 4; ++j) {
            #pragma unroll
            for (int c = 0; c < 4; ++c) {
                float v = (&e[j].x)[c];
                int   ix = col0 + c + 512 * j;
                if (v > bv || (v == bv && ix < bi)) { rv = bv; ri = bi; bv = v; bi = ix; }
                else if (v > rv || (v == rv && ix < ri)) { rv = v; ri = ix; }
            }
        }
        // ---- wave butterfly top-2 ----
        #pragma unroll
        for (int off = 32; off; off >>= 1) {
            float obv = __shfl_xor(bv, off, 64);
            int   obi = __shfl_xor(bi, off, 64);
            float orv = __shfl_xor(rv, off, 64);
            int   ori = __shfl_xor(ri, off, 64);
            bool ob = (obv > bv) || (obv == bv && obi < bi);
            float c1v = ob ? bv : obv;  int c1i = ob ? bi : obi;
            float c2v = ob ? orv : rv;  int c2i = ob ? ori : ri;
            bv = ob ? obv : bv;  bi = ob ? obi : bi;
            bool rb = (c1v > c2v) || (c1v == c2v && c1i < c2i);
            rv = rb ? c1v : c2v;  ri = rb ? c1i : c2i;
        }
        if ((t & 63) == 0) {
            redv[w][0] = bv; redv[w][1] = rv;
            redi[w][0] = bi; redi[w][1] = ri;
        }
        __syncthreads();
        // ---- cross-wave (team) top-2 combine, computed by every team lane ----
        {
            float b0 = redv[w0][0], r0 = redv[w0][1];
            int   i0 = redi[w0][0], j0 = redi[w0][1];
            float b1 = redv[w1][0], r1 = redv[w1][1];
            int   i1 = redi[w1][0], j1 = redi[w1][1];
            bool ob = (b1 > b0) || (b1 == b0 && i1 < i0);
            bv = ob ? b1 : b0;  bi = ob ? i1 : i0;
            float c1v = ob ? b0 : b1;  int c1i = ob ? i0 : i1;   // loser best
            float c2v = ob ? r1 : r0;  int c2i = ob ? j1 : j0;   // winner runner
            bool rb = (c1v > c2v) || (c1v == c2v && c1i < c2i);
            rv = rb ? c1v : c2v;  ri = rb ? c1i : c2i;
        }
        const float m = bv;

        // ---- softmax stats ----
        float Z = 0.f, S = 0.f;
        #pragma unroll
        for (int j = 0; j < 4; ++j) {
            #pragma unroll
            for (int c = 0; c < 4; ++c) {
                float d = (&e[j].x)[c] - m;
                float ex = expf(d);
                Z += ex; S += ex * d;
                (&e[j].x)[c] = ex;
            }
        }
        #pragma unroll
        for (int off = 32; off; off >>= 1) {
            Z += __shfl_xor(Z, off, 64);
            S += __shfl_xor(S, off, 64);
        }
        if ((t & 63) == 0) { zs[w][0] = Z; zs[w][1] = S; }
        __syncthreads();
        Z = zs[w0][0] + zs[w1][0];
        S = zs[w0][1] + zs[w1][1];
        const float inv = 1.0f / Z;
        #pragma unroll
        for (int j = 0; j < 4; ++j) {
            dacc[j].x += e[j].x * inv; dacc[j].y += e[j].y * inv;
            dacc[j].z += e[j].z * inv; dacc[j].w += e[j].w * inv;
        }

        if (tl == 0) {
            // sum p*log2(p+1e-8) = log2e*(S/Z) - log2(Z) + 2048*1e-8*log2e
            ent_acc += 1.4426950408889634f * (S * inv) - log2f(Z) + 2.9546393e-5f;
            atomicAdd(&counts[bi], 1);
            nn[row] = (float)bi;
            if (bv - rv < FLAG_TAU) {
                int fe = atomicAdd(nflag, 1);
                if (fe < FLAG_CAP) {
                    flags[3*fe] = row; flags[3*fe+1] = bi; flags[3*fe+2] = ri;
                }
            }
        }
    }

    if (tl == 0) sent[team] = ent_acc;
    // combine 2 teams' diversity in LDS (deterministic), then atomic to global
    if (team == 0) {
        #pragma unroll
        for (int j = 0; j < 4; ++j) *(float4*)&divp[col0 + 512 * j] = dacc[j];
    }
    __syncthreads();
    if (team == 1) {
        #pragma unroll
        for (int j = 0; j < 4; ++j) {
            float4 v = *(float4*)&divp[col0 + 512 * j];
            v.x += dacc[j].x; v.y += dacc[j].y; v.z += dacc[j].z; v.w += dacc[j].w;
            *(float4*)&divp[col0 + 512 * j] = v;
        }
    }
    __syncthreads();
    #pragma unroll
    for (int k = 0; k < 8; ++k) atomicAdd(&div[t * 8 + k], divp[t * 8 + k]);
    if (t == 0) entpart[b] = sent[0] + sent[1];
}

// ----------------------------------------------------------------- fixup ----
__global__ __launch_bounds__(256) void fixflag(const float* __restrict__ A,
                                               const float* __restrict__ B,
                                               float* __restrict__ nn,
                                               int*   __restrict__ counts,
                                               const int* __restrict__ flags,
                                               const int* __restrict__ nflagp) {
    __shared__ float sf[4];
    int nf = *nflagp; if (nf > FLAG_CAP) nf = FLAG_CAP;
    const int t = threadIdx.x, lane = t & 63, w = t >> 6;
    for (int e = blockIdx.x; e < nf; e += gridDim.x) {
        const int row = flags[3*e], i1 = flags[3*e+1], i2 = flags[3*e+2];
        const float* ar = A + (size_t)row * DIM;
        const float* b1 = B + (size_t)i1 * DIM;
        const float* b2 = B + (size_t)i2 * DIM;
        float d1 = ar[t] * b1[t] + ar[t + 256] * b1[t + 256];
        float d2 = ar[t] * b2[t] + ar[t + 256] * b2[t + 256];
        d1 = block_reduce_sum(d1, sf, lane, w);
        d2 = block_reduce_sum(d2, sf, lane, w);
        if (t == 0 && (d2 > d1 || (d2 == d1 && i2 < i1))) {
            nn[row] = (float)i2;
            atomicSub(&counts[i1], 1);
            atomicAdd(&counts[i2], 1);
        }
        __syncthreads();
    }
}

// ------------------------------------------------------------- finalize -----
__global__ __launch_bounds__(256) void fin(const float* __restrict__ div,
                                           const float* __restrict__ entpart,
                                           float* __restrict__ lossp) {
    __shared__ float sf[4];
    const int t = threadIdx.x, lane = t & 63, w = t >> 6;
    float loc = 0.f;
    #pragma unroll
    for (int k = 0; k < 8; ++k) {
        float d = div[t + 256 * k] * (1.0f / 16384.0f);
        loc += d * log2f(d + 1e-8f);
    }
    float Sd = block_reduce_sum(loc, sf, lane, w);
    float se = entpart[t] + entpart[t + 256] + entpart[t + 512] + entpart[t + 768];
    float Se = block_reduce_sum(se, sf, lane, w);
    if (t == 0)
        lossp[0] = (float)(-(double)Se / 16384.0 + (double)Sd);
}

// ------------------------------------------------------- quantize+epilogue --
__global__ __launch_bounds__(256) void tail(const float* __restrict__ cb,
                                            const float* __restrict__ oldc,
                                            const int*   __restrict__ counts,
                                            const float* __restrict__ lossp,
                                            const int*   __restrict__ train,
                                            const float* __restrict__ nn,
                                            float* __restrict__ out) {
    const int bb = blockIdx.x;
    const int t  = threadIdx.x;
    if (bb < 4096) {
        // quantize 4 rows/block; STE output == q_norm exactly (x+(q-x)=q)
        const int lane = t & 63;
        const int row  = (bb << 2) + (t >> 6);
        const int idx  = (int)nn[row];
        const float* c = cb + (size_t)idx * DIM;

        float4 q0 = *(const float4*)(c + lane * 8);
        float4 q1 = *(const float4*)(c + lane * 8 + 4);

        float s = q0.x+q0.y+q0.z+q0.w + q1.x+q1.y+q1.z+q1.w;
        #pragma unroll
        for (int off = 32; off; off >>= 1) s += __shfl_xor(s, off, 64);
        const float mean = s * (1.0f / 512.0f);
        q0.x -= mean; q0.y -= mean; q0.z -= mean; q0.w -= mean;
        q1.x -= mean; q1.y -= mean; q1.z -= mean; q1.w -= mean;

        float ss = q0.x*q0.x+q0.y*q0.y+q0.z*q0.z+q0.w*q0.w
                 + q1.x*q1.x+q1.y*q1.y+q1.z*q1.z+q1.w*q1.w;
        #pragma unroll
        for (int off = 32; off; off >>= 1) ss += __shfl_xor(ss, off, 64);
        const float inv = 1.0f / sqrtf(ss);

        float4 o0, o1;
        o0.x = q0.x*inv; o0.y = q0.y*inv; o0.z = q0.z*inv; o0.w = q0.w*inv;
        o1.x = q1.x*inv; o1.y = q1.y*inv; o1.z = q1.z*inv; o1.w = q1.w*inv;
        *(float4*)(out + (size_t)row * DIM + lane * 8)     = o0;
        *(float4*)(out + (size_t)row * DIM + lane * 8 + 4) = o1;
    } else {
        const size_t LOSS4 = 33554432ul / 4;
        const size_t CB4   = 1048576ul  / 4;
        size_t i = (size_t)(bb - 4096) * 256 + t;
        if (i < LOSS4) {
            const float l = lossp[0];
            ((float4*)(out + LOSS_OFF))[i] = make_float4(l, l, l, l);
        } else if (i < LOSS4 + CB4) {
            size_t j = i - LOSS4;
            ((float4*)(out + CB_OFF))[j] = ((const float4*)cb)[j];
        } else {
            size_t k = i - LOSS4 - CB4;
            if (k < 2048) {
                float nc = train[0] ? 0.99f * oldc[k] + 0.01f * (float)counts[k]
                                    : oldc[k];
                out[CNT_OFF + k] = nc;
            }
        }
    }
}

// ------------------------------------------------------------------ launch --
extern "C" void kernel_launch(void* const* d_in, const int* in_sizes, int n_in,
                              void* d_out, int out_size, void* d_ws, size_t ws_size,
                              hipStream_t stream) {
    const float* x     = (const float*)d_in[0];
    const float* cb    = (const float*)d_in[1];
    const float* oldc  = (const float*)d_in[2];
    const int*   train = (const int*)d_in[3];
    float* out = (float*)d_out;

    float* sim = out + LOSS_OFF;
    float* nn  = out + NN_OFF;

    float* lossp   = (float*)d_ws + WS_LOSS;
    int*   counts  = (int*)d_ws   + WS_CNT;
    float* div     = (float*)d_ws + WS_DIV;
    float* entpart = (float*)d_ws + WS_ENT;
    int*   nflag   = (int*)d_ws   + WS_NFLAG;
    int*   flags   = (int*)d_ws   + WS_FLAGS;

    gemm_mfma<<<dim3(KC / 128, NROWS / 128), 256, 0, stream>>>(x, cb, sim, (int*)d_ws);
    rowpass<<<1024, 256, 0, stream>>>(sim, nn, div, counts, entpart, nflag, flags);
    fixflag<<<128, 256, 0, stream>>>(x, cb, nn, counts, flags, nflag);
    fin<<<1, 256, 0, stream>>>(div, entpart, lossp);
    tail<<<4096 + 33800, 256, 0, stream>>>(cb, oldc, counts, lossp, train, nn, out);
}

// Round 8
// 546.003 us; speedup vs baseline: 1.0270x; 1.0270x over previous
//
#include <hip/hip_runtime.h>
#include <cstddef>
#include <cmath>

// Problem constants
#define NROWS 16384   // 32*512
#define DIM   512
#define KC    2048

// d_out layout (float32 element offsets)
#define Q_OFF    0ul
#define LOSS_OFF 8388608ul    // 33,554,432 elems (reused as sim scratch)
#define NN_OFF   41943040ul   // 16,384 elems
#define CB_OFF   41959424ul   // 1,048,576 elems
#define CNT_OFF  43008000ul   // 2,048 elems

#define FLAG_CAP 4096
#define FLAG_TAU 3e-5f        // 3-term split: argmax errors ~1e-6; proven r1-r3/r5

// ws layout (32-bit slots)
#define WS_LOSS   0
#define WS_CNT    4       // 2048 ints
#define WS_DIV    2052    // 2048 floats (fp32-atomic diversity column sums)
#define WS_ENT    4100    // 1024 floats (per-block entropy partials)
#define WS_NFLAG  5124
#define WS_FLAGS  5128    // 3*4096 ints
#define WS_ZEND   5128    // zero range [0, WS_ZEND)

typedef __attribute__((ext_vector_type(8))) short short8;
typedef __attribute__((ext_vector_type(4))) float f32x4;

// NT-store helper: __builtin_nontemporal_store needs clang vector types,
// not HIP_vector_type<float,4>.
__device__ __forceinline__ void nt_store4(float* p, float4 v) {
    f32x4 u; u[0] = v.x; u[1] = v.y; u[2] = v.z; u[3] = v.w;
    __builtin_nontemporal_store(u, (f32x4*)p);
}

// ----------------------------------------------------------- bf16 split -----
__device__ __forceinline__ short hi1(float f) {
    return (short)(__float_as_uint(f) >> 16);
}
__device__ __forceinline__ short lo1(float f) {
    unsigned int u = __float_as_uint(f);
    float l = f - __uint_as_float(u & 0xffff0000u);
    return (short)(__float_as_uint(l) >> 16);
}
__device__ __forceinline__ short8 hi8(float4 a, float4 b) {
    short8 r;
    r[0]=hi1(a.x); r[1]=hi1(a.y); r[2]=hi1(a.z); r[3]=hi1(a.w);
    r[4]=hi1(b.x); r[5]=hi1(b.y); r[6]=hi1(b.z); r[7]=hi1(b.w);
    return r;
}
__device__ __forceinline__ short8 lo8(float4 a, float4 b) {
    short8 r;
    r[0]=lo1(a.x); r[1]=lo1(a.y); r[2]=lo1(a.z); r[3]=lo1(a.w);
    r[4]=lo1(b.x); r[5]=lo1(b.y); r[6]=lo1(b.z); r[7]=lo1(b.w);
    return r;
}

// ---------------------------------------------------------------- GEMM ------
// sim = A x B^T via bf16 hi/lo 3-term split: Ah*Bh + Al*Bh + Ah*Bl. (known-good)
#define LDW  40
#define AH_B 0
#define AL_B 5120
#define BH_B 10240
#define BL_B 15360

__global__ __launch_bounds__(256, 3) void gemm_mfma(const float* __restrict__ A,
                                                    const float* __restrict__ B,
                                                    float* __restrict__ C,
                                                    int* __restrict__ ws) {
    if (blockIdx.x == 0 && blockIdx.y == 0) {
        for (int i = threadIdx.x; i < WS_ZEND; i += 256) ws[i] = 0;
    }
    __shared__ ushort smem[20480];   // 40 KB
    const int t    = threadIdx.x;
    const int n0   = blockIdx.x * 128;
    const int m0   = blockIdx.y * 128;
    const int rsub = t >> 2;
    const int kc   = (t & 3) * 8;
    const int lane = t & 63, quad = lane >> 4, lr = lane & 15;
    const int w = t >> 6, wm = w >> 1, wn = w & 1;

    f32x4 acc[4][4] = {};

    const float* Abase = A + (size_t)(m0 + rsub) * DIM + kc;
    const float* Bbase = B + (size_t)(n0 + rsub) * DIM + kc;

    float4 pa0 = *(const float4*)(Abase);
    float4 pa1 = *(const float4*)(Abase + 4);
    float4 pa2 = *(const float4*)(Abase + 64 * DIM);
    float4 pa3 = *(const float4*)(Abase + 64 * DIM + 4);
    float4 pb0 = *(const float4*)(Bbase);
    float4 pb1 = *(const float4*)(Bbase + 4);
    float4 pb2 = *(const float4*)(Bbase + 64 * DIM);
    float4 pb3 = *(const float4*)(Bbase + 64 * DIM + 4);

    ushort* wa0 = smem + AH_B + rsub * LDW + kc;
    ushort* wa1 = smem + AH_B + (rsub + 64) * LDW + kc;
    ushort* wb0 = smem + BH_B + rsub * LDW + kc;
    ushort* wb1 = smem + BH_B + (rsub + 64) * LDW + kc;

    const ushort* ra = smem + (wm * 64 + lr) * LDW + quad * 8;
    const ushort* rb = smem + (wn * 64 + lr) * LDW + quad * 8;

    for (int kk = 0; kk < 16; ++kk) {
        *(short8*)(wa0)        = hi8(pa0, pa1);
        *(short8*)(wa0 + AL_B) = lo8(pa0, pa1);
        *(short8*)(wa1)        = hi8(pa2, pa3);
        *(short8*)(wa1 + AL_B) = lo8(pa2, pa3);
        *(short8*)(wb0)        = hi8(pb0, pb1);
        *(short8*)(wb0 + AL_B) = lo8(pb0, pb1);
        *(short8*)(wb1)        = hi8(pb2, pb3);
        *(short8*)(wb1 + AL_B) = lo8(pb2, pb3);
        __syncthreads();

        if (kk < 15) {
            const float* a = Abase + (kk + 1) * 32;
            const float* b = Bbase + (kk + 1) * 32;
            pa0 = *(const float4*)(a);
            pa1 = *(const float4*)(a + 4);
            pa2 = *(const float4*)(a + 64 * DIM);
            pa3 = *(const float4*)(a + 64 * DIM + 4);
            pb0 = *(const float4*)(b);
            pb1 = *(const float4*)(b + 4);
            pb2 = *(const float4*)(b + 64 * DIM);
            pb3 = *(const float4*)(b + 64 * DIM + 4);
        }

        short8 ah[4], al[4], bx[4];
        #pragma unroll
        for (int mt = 0; mt < 4; ++mt) ah[mt] = *(const short8*)(ra + AH_B + mt * 16 * LDW);
        #pragma unroll
        for (int nt = 0; nt < 4; ++nt) bx[nt] = *(const short8*)(rb + BH_B + nt * 16 * LDW);
        #pragma unroll
        for (int mt = 0; mt < 4; ++mt)
            #pragma unroll
            for (int nt = 0; nt < 4; ++nt)
                acc[mt][nt] = __builtin_amdgcn_mfma_f32_16x16x32_bf16(ah[mt], bx[nt], acc[mt][nt], 0, 0, 0);
        #pragma unroll
        for (int mt = 0; mt < 4; ++mt) al[mt] = *(const short8*)(ra + AL_B + mt * 16 * LDW);
        #pragma unroll
        for (int mt = 0; mt < 4; ++mt)
            #pragma unroll
            for (int nt = 0; nt < 4; ++nt)
                acc[mt][nt] = __builtin_amdgcn_mfma_f32_16x16x32_bf16(al[mt], bx[nt], acc[mt][nt], 0, 0, 0);
        #pragma unroll
        for (int nt = 0; nt < 4; ++nt) bx[nt] = *(const short8*)(rb + BL_B + nt * 16 * LDW);
        #pragma unroll
        for (int mt = 0; mt < 4; ++mt)
            #pragma unroll
            for (int nt = 0; nt < 4; ++nt)
                acc[mt][nt] = __builtin_amdgcn_mfma_f32_16x16x32_bf16(ah[mt], bx[nt], acc[mt][nt], 0, 0, 0);
        __syncthreads();
    }

    #pragma unroll
    for (int mt = 0; mt < 4; ++mt) {
        #pragma unroll
        for (int nt = 0; nt < 4; ++nt) {
            const int r0 = m0 + wm * 64 + mt * 16 + quad * 4;
            const int c0 = n0 + wn * 64 + nt * 16 + lr;
            #pragma unroll
            for (int j = 0; j < 4; ++j)
                C[(size_t)(r0 + j) * KC + c0] = acc[mt][nt][j];
        }
    }
}

// ------------------------------------------------------------ block reduce --
__device__ __forceinline__ float block_reduce_sum(float v, volatile float* sf,
                                                  int lane, int w) {
    #pragma unroll
    for (int off = 32; off; off >>= 1) v += __shfl_xor(v, off, 64);
    if (lane == 0) sf[w] = v;
    __syncthreads();
    v = sf[0] + sf[1] + sf[2] + sf[3];
    __syncthreads();
    return v;
}

// ---------------------------------------------------------------- row pass --
// r5 wave-private structure (r6 team split was latency-bound). One row per
// wave, 8 loads/lane in flight, no intra-loop syncthreads. Diversity: LDS
// combine + global fp32 atomicAdd (loss path only, ~1e-5 error).
__global__ __launch_bounds__(256, 4) void rowpass(const float* __restrict__ sim,
                                                  float* __restrict__ nn,
                                                  float* __restrict__ div,       // ws [2048]
                                                  int*   __restrict__ counts,    // ws [2048]
                                                  float* __restrict__ entpart,   // ws [1024]
                                                  int*   __restrict__ nflag,
                                                  int*   __restrict__ flags) {
    __shared__ float divp[KC];
    __shared__ float sent[4];
    const int t = threadIdx.x, lane = t & 63, w = t >> 6;
    const int b = blockIdx.x;
    const int row0 = b * 16 + w * 4;
    const int col0 = lane << 2;

    float4 dacc[8] = {};
    float ent_acc = 0.f;
    const float* base = sim + (size_t)row0 * KC + col0;

    #pragma unroll 1
    for (int rr = 0; rr < 4; ++rr) {
        float4 cur[8];
        const float* rp = base + (size_t)rr * KC;
        #pragma unroll
        for (int j = 0; j < 8; ++j) cur[j] = *(const float4*)(rp + 256 * j);

        // ---- top-2 (value, index), first-occurrence tie rule ----
        float bv = -3.0e38f, rv = -3.0e38f;
        int   bi = 0x7fffffff, ri = 0x7fffffff;
        #pragma unroll
        for (int j = 0; j < 8; ++j) {
            #pragma unroll
            for (int c = 0; c < 4; ++c) {
                float v = (&cur[j].x)[c];
                int   i = col0 + c + 256 * j;
                if (v > bv || (v == bv && i < bi)) { rv = bv; ri = bi; bv = v; bi = i; }
                else if (v > rv || (v == rv && i < ri)) { rv = v; ri = i; }
            }
        }
        #pragma unroll
        for (int off = 32; off; off >>= 1) {
            float obv = __shfl_xor(bv, off, 64);
            int   obi = __shfl_xor(bi, off, 64);
            float orv = __shfl_xor(rv, off, 64);
            int   ori = __shfl_xor(ri, off, 64);
            bool ob = (obv > bv) || (obv == bv && obi < bi);
            float c1v = ob ? bv : obv;  int c1i = ob ? bi : obi;
            float c2v = ob ? orv : rv;  int c2i = ob ? ori : ri;
            bv = ob ? obv : bv;  bi = ob ? obi : bi;
            bool rb = (c1v > c2v) || (c1v == c2v && c1i < c2i);
            rv = rb ? c1v : c2v;  ri = rb ? c1i : c2i;
        }
        const float m = bv;

        // ---- softmax stats: Z = sum e, S = sum e*(s-m) ----
        float Z = 0.f, S = 0.f;
        #pragma unroll
        for (int j = 0; j < 8; ++j) {
            #pragma unroll
            for (int c = 0; c < 4; ++c) {
                float d = (&cur[j].x)[c] - m;
                float e = expf(d);
                Z += e; S += e * d;
                (&cur[j].x)[c] = e;
            }
        }
        #pragma unroll
        for (int off = 32; off; off >>= 1) {
            Z += __shfl_xor(Z, off, 64);
            S += __shfl_xor(S, off, 64);
        }
        const float inv = 1.0f / Z;
        #pragma unroll
        for (int j = 0; j < 8; ++j) {
            dacc[j].x += cur[j].x * inv; dacc[j].y += cur[j].y * inv;
            dacc[j].z += cur[j].z * inv; dacc[j].w += cur[j].w * inv;
        }

        if (lane == 0) {
            // sum p*log2(p+1e-8) = log2e*(S/Z) - log2(Z) + 2048*1e-8*log2e
            ent_acc += 1.4426950408889634f * (S * inv) - log2f(Z) + 2.9546393e-5f;
            atomicAdd(&counts[bi], 1);
            nn[row0 + rr] = (float)bi;
            if (bv - rv < FLAG_TAU) {
                int e = atomicAdd(nflag, 1);
                if (e < FLAG_CAP) {
                    flags[3*e] = row0 + rr; flags[3*e+1] = bi; flags[3*e+2] = ri;
                }
            }
        }
    }

    if (lane == 0) sent[w] = ent_acc;
    // deterministic cross-wave diversity combine in LDS, then atomic to global
    for (int ww = 0; ww < 4; ++ww) {
        if (w == ww) {
            #pragma unroll
            for (int j = 0; j < 8; ++j) {
                float4* p = (float4*)&divp[col0 + 256 * j];
                if (ww == 0) *p = dacc[j];
                else {
                    float4 v = *p;
                    v.x += dacc[j].x; v.y += dacc[j].y;
                    v.z += dacc[j].z; v.w += dacc[j].w;
                    *p = v;
                }
            }
        }
        __syncthreads();
    }
    #pragma unroll
    for (int k = 0; k < 8; ++k) atomicAdd(&div[t * 8 + k], divp[t * 8 + k]);
    if (t == 0) entpart[b] = sent[0] + sent[1] + sent[2] + sent[3];
}

// ----------------------------------------- fixup + loss finalize (merged) ---
// blocks 0..127: exact fp32 re-check of flagged near-tie rows
// block 128:     loss = -mean(ent) - gamma*h_div  (independent data)
__global__ __launch_bounds__(256) void fixfin(const float* __restrict__ A,
                                              const float* __restrict__ B,
                                              float* __restrict__ nn,
                                              int*   __restrict__ counts,
                                              const int* __restrict__ flags,
                                              const int* __restrict__ nflagp,
                                              const float* __restrict__ div,
                                              const float* __restrict__ entpart,
                                              float* __restrict__ lossp) {
    __shared__ float sf[4];
    const int t = threadIdx.x, lane = t & 63, w = t >> 6;
    if (blockIdx.x == 128) {
        float loc = 0.f;
        #pragma unroll
        for (int k = 0; k < 8; ++k) {
            float d = div[t + 256 * k] * (1.0f / 16384.0f);
            loc += d * log2f(d + 1e-8f);
        }
        float Sd = block_reduce_sum(loc, sf, lane, w);
        float se = entpart[t] + entpart[t + 256] + entpart[t + 512] + entpart[t + 768];
        float Se = block_reduce_sum(se, sf, lane, w);
        if (t == 0)
            lossp[0] = (float)(-(double)Se / 16384.0 + (double)Sd);
        return;
    }
    int nf = *nflagp; if (nf > FLAG_CAP) nf = FLAG_CAP;
    for (int e = blockIdx.x; e < nf; e += 128) {
        const int row = flags[3*e], i1 = flags[3*e+1], i2 = flags[3*e+2];
        const float* ar = A + (size_t)row * DIM;
        const float* b1 = B + (size_t)i1 * DIM;
        const float* b2 = B + (size_t)i2 * DIM;
        float d1 = ar[t] * b1[t] + ar[t + 256] * b1[t + 256];
        float d2 = ar[t] * b2[t] + ar[t + 256] * b2[t + 256];
        d1 = block_reduce_sum(d1, sf, lane, w);
        d2 = block_reduce_sum(d2, sf, lane, w);
        if (t == 0 && (d2 > d1 || (d2 == d1 && i2 < i1))) {
            nn[row] = (float)i2;
            atomicSub(&counts[i1], 1);
            atomicAdd(&counts[i2], 1);
        }
        __syncthreads();
    }
}

// ------------------------------------------------------- quantize+epilogue --
__global__ __launch_bounds__(256) void tail(const float* __restrict__ cb,
                                            const float* __restrict__ oldc,
                                            const int*   __restrict__ counts,
                                            const float* __restrict__ lossp,
                                            const int*   __restrict__ train,
                                            const float* __restrict__ nn,
                                            float* __restrict__ out) {
    const int bb = blockIdx.x;
    const int t  = threadIdx.x;
    if (bb < 4096) {
        // quantize 4 rows/block; STE output == q_norm exactly (x+(q-x)=q)
        const int lane = t & 63;
        const int row  = (bb << 2) + (t >> 6);
        const int idx  = (int)nn[row];
        const float* c = cb + (size_t)idx * DIM;

        float4 q0 = *(const float4*)(c + lane * 8);
        float4 q1 = *(const float4*)(c + lane * 8 + 4);

        float s = q0.x+q0.y+q0.z+q0.w + q1.x+q1.y+q1.z+q1.w;
        #pragma unroll
        for (int off = 32; off; off >>= 1) s += __shfl_xor(s, off, 64);
        const float mean = s * (1.0f / 512.0f);
        q0.x -= mean; q0.y -= mean; q0.z -= mean; q0.w -= mean;
        q1.x -= mean; q1.y -= mean; q1.z -= mean; q1.w -= mean;

        float ss = q0.x*q0.x+q0.y*q0.y+q0.z*q0.z+q0.w*q0.w
                 + q1.x*q1.x+q1.y*q1.y+q1.z*q1.z+q1.w*q1.w;
        #pragma unroll
        for (int off = 32; off; off >>= 1) ss += __shfl_xor(ss, off, 64);
        const float inv = 1.0f / sqrtf(ss);

        float4 o0, o1;
        o0.x = q0.x*inv; o0.y = q0.y*inv; o0.z = q0.z*inv; o0.w = q0.w*inv;
        o1.x = q1.x*inv; o1.y = q1.y*inv; o1.z = q1.z*inv; o1.w = q1.w*inv;
        nt_store4(out + (size_t)row * DIM + lane * 8, o0);
        nt_store4(out + (size_t)row * DIM + lane * 8 + 4, o1);
    } else {
        const size_t LOSS4 = 33554432ul / 4;
        const size_t CB4   = 1048576ul  / 4;
        size_t i = (size_t)(bb - 4096) * 256 + t;
        if (i < LOSS4) {
            const float l = lossp[0];
            nt_store4(out + LOSS_OFF + i * 4, make_float4(l, l, l, l));
        } else if (i < LOSS4 + CB4) {
            size_t j = i - LOSS4;
            nt_store4(out + CB_OFF + j * 4, ((const float4*)cb)[j]);
        } else {
            size_t k = i - LOSS4 - CB4;
            if (k < 2048) {
                float nc = train[0] ? 0.99f * oldc[k] + 0.01f * (float)counts[k]
                                    : oldc[k];
                out[CNT_OFF + k] = nc;
            }
        }
    }
}

// ------------------------------------------------------------------ launch --
extern "C" void kernel_launch(void* const* d_in, const int* in_sizes, int n_in,
                              void* d_out, int out_size, void* d_ws, size_t ws_size,
                              hipStream_t stream) {
    const float* x     = (const float*)d_in[0];
    const float* cb    = (const float*)d_in[1];
    const float* oldc  = (const float*)d_in[2];
    const int*   train = (const int*)d_in[3];
    float* out = (float*)d_out;

    float* sim = out + LOSS_OFF;
    float* nn  = out + NN_OFF;

    float* lossp   = (float*)d_ws + WS_LOSS;
    int*   counts  = (int*)d_ws   + WS_CNT;
    float* div     = (float*)d_ws + WS_DIV;
    float* entpart = (float*)d_ws + WS_ENT;
    int*   nflag   = (int*)d_ws   + WS_NFLAG;
    int*   flags   = (int*)d_ws   + WS_FLAGS;

    gemm_mfma<<<dim3(KC / 128, NROWS / 128), 256, 0, stream>>>(x, cb, sim, (int*)d_ws);
    rowpass<<<1024, 256, 0, stream>>>(sim, nn, div, counts, entpart, nflag, flags);
    fixfin<<<129, 256, 0, stream>>>(x, cb, nn, counts, flags, nflag, div, entpart, lossp);
    tail<<<4096 + 33800, 256, 0, stream>>>(cb, oldc, counts, lossp, train, nn, out);
}

// Round 9
// 368.219 us; speedup vs baseline: 1.5229x; 1.4828x over previous
//
#include <hip/hip_runtime.h>
#include <cstddef>
#include <cmath>

// Problem constants
#define NROWS 16384   // 32*512
#define DIM   512
#define KC    2048

// d_out layout (float32 element offsets)
#define Q_OFF    0ul          // 8,388,608 elems (reused: divpart2 [2048][2048])
#define LOSS_OFF 8388608ul    // 33,554,432 elems (reused as sim scratch)
#define NN_OFF   41943040ul   // 16,384 elems
#define CB_OFF   41959424ul   // 1,048,576 elems (reused: part2 [256][2048])
#define CNT_OFF  43008000ul   // 2,048 elems

#define FLAG_CAP 4096
#define FLAG_TAU 3e-5f        // 3-term split: argmax errors ~1e-6; proven r1-r3/r5

// ws layout (32-bit slots)
#define WS_LOSS   0
#define WS_CNT    4       // 2048 ints
#define WS_ENT    2052    // 2048 floats (per-block entropy partials)
#define WS_NFLAG  4100
#define WS_FLAGS  4104    // 3*4096 ints
#define WS_DIVLOG 16392   // 8 floats
#define WS_SE     16400   // 1 float
#define WS_ZEND   4104    // zero range [0, WS_ZEND) covers loss+cnt+ent+nflag

typedef __attribute__((ext_vector_type(8))) short short8;
typedef __attribute__((ext_vector_type(4))) float f32x4;

// NT-store helper (__builtin_nontemporal_store needs clang vector types)
__device__ __forceinline__ void nt_store4(float* p, float4 v) {
    f32x4 u; u[0] = v.x; u[1] = v.y; u[2] = v.z; u[3] = v.w;
    __builtin_nontemporal_store(u, (f32x4*)p);
}

// ----------------------------------------------------------- bf16 split -----
__device__ __forceinline__ short hi1(float f) {
    return (short)(__float_as_uint(f) >> 16);
}
__device__ __forceinline__ short lo1(float f) {
    unsigned int u = __float_as_uint(f);
    float l = f - __uint_as_float(u & 0xffff0000u);
    return (short)(__float_as_uint(l) >> 16);
}
__device__ __forceinline__ short8 hi8(float4 a, float4 b) {
    short8 r;
    r[0]=hi1(a.x); r[1]=hi1(a.y); r[2]=hi1(a.z); r[3]=hi1(a.w);
    r[4]=hi1(b.x); r[5]=hi1(b.y); r[6]=hi1(b.z); r[7]=hi1(b.w);
    return r;
}
__device__ __forceinline__ short8 lo8(float4 a, float4 b) {
    short8 r;
    r[0]=lo1(a.x); r[1]=lo1(a.y); r[2]=lo1(a.z); r[3]=lo1(a.w);
    r[4]=lo1(b.x); r[5]=lo1(b.y); r[6]=lo1(b.z); r[7]=lo1(b.w);
    return r;
}

// ---------------------------------------------------------------- GEMM ------
// sim = A x B^T via bf16 hi/lo 3-term split: Ah*Bh + Al*Bh + Ah*Bl. (known-good)
#define LDW  40
#define AH_B 0
#define AL_B 5120
#define BH_B 10240
#define BL_B 15360

__global__ __launch_bounds__(256, 3) void gemm_mfma(const float* __restrict__ A,
                                                    const float* __restrict__ B,
                                                    float* __restrict__ C,
                                                    int* __restrict__ ws) {
    if (blockIdx.x == 0 && blockIdx.y == 0) {
        for (int i = threadIdx.x; i < WS_ZEND; i += 256) ws[i] = 0;
    }
    __shared__ ushort smem[20480];   // 40 KB
    const int t    = threadIdx.x;
    const int n0   = blockIdx.x * 128;
    const int m0   = blockIdx.y * 128;
    const int rsub = t >> 2;
    const int kc   = (t & 3) * 8;
    const int lane = t & 63, quad = lane >> 4, lr = lane & 15;
    const int w = t >> 6, wm = w >> 1, wn = w & 1;

    f32x4 acc[4][4] = {};

    const float* Abase = A + (size_t)(m0 + rsub) * DIM + kc;
    const float* Bbase = B + (size_t)(n0 + rsub) * DIM + kc;

    float4 pa0 = *(const float4*)(Abase);
    float4 pa1 = *(const float4*)(Abase + 4);
    float4 pa2 = *(const float4*)(Abase + 64 * DIM);
    float4 pa3 = *(const float4*)(Abase + 64 * DIM + 4);
    float4 pb0 = *(const float4*)(Bbase);
    float4 pb1 = *(const float4*)(Bbase + 4);
    float4 pb2 = *(const float4*)(Bbase + 64 * DIM);
    float4 pb3 = *(const float4*)(Bbase + 64 * DIM + 4);

    ushort* wa0 = smem + AH_B + rsub * LDW + kc;
    ushort* wa1 = smem + AH_B + (rsub + 64) * LDW + kc;
    ushort* wb0 = smem + BH_B + rsub * LDW + kc;
    ushort* wb1 = smem + BH_B + (rsub + 64) * LDW + kc;

    const ushort* ra = smem + (wm * 64 + lr) * LDW + quad * 8;
    const ushort* rb = smem + (wn * 64 + lr) * LDW + quad * 8;

    for (int kk = 0; kk < 16; ++kk) {
        *(short8*)(wa0)        = hi8(pa0, pa1);
        *(short8*)(wa0 + AL_B) = lo8(pa0, pa1);
        *(short8*)(wa1)        = hi8(pa2, pa3);
        *(short8*)(wa1 + AL_B) = lo8(pa2, pa3);
        *(short8*)(wb0)        = hi8(pb0, pb1);
        *(short8*)(wb0 + AL_B) = lo8(pb0, pb1);
        *(short8*)(wb1)        = hi8(pb2, pb3);
        *(short8*)(wb1 + AL_B) = lo8(pb2, pb3);
        __syncthreads();

        if (kk < 15) {
            const float* a = Abase + (kk + 1) * 32;
            const float* b = Bbase + (kk + 1) * 32;
            pa0 = *(const float4*)(a);
            pa1 = *(const float4*)(a + 4);
            pa2 = *(const float4*)(a + 64 * DIM);
            pa3 = *(const float4*)(a + 64 * DIM + 4);
            pb0 = *(const float4*)(b);
            pb1 = *(const float4*)(b + 4);
            pb2 = *(const float4*)(b + 64 * DIM);
            pb3 = *(const float4*)(b + 64 * DIM + 4);
        }

        short8 ah[4], al[4], bx[4];
        #pragma unroll
        for (int mt = 0; mt < 4; ++mt) ah[mt] = *(const short8*)(ra + AH_B + mt * 16 * LDW);
        #pragma unroll
        for (int nt = 0; nt < 4; ++nt) bx[nt] = *(const short8*)(rb + BH_B + nt * 16 * LDW);
        #pragma unroll
        for (int mt = 0; mt < 4; ++mt)
            #pragma unroll
            for (int nt = 0; nt < 4; ++nt)
                acc[mt][nt] = __builtin_amdgcn_mfma_f32_16x16x32_bf16(ah[mt], bx[nt], acc[mt][nt], 0, 0, 0);
        #pragma unroll
        for (int mt = 0; mt < 4; ++mt) al[mt] = *(const short8*)(ra + AL_B + mt * 16 * LDW);
        #pragma unroll
        for (int mt = 0; mt < 4; ++mt)
            #pragma unroll
            for (int nt = 0; nt < 4; ++nt)
                acc[mt][nt] = __builtin_amdgcn_mfma_f32_16x16x32_bf16(al[mt], bx[nt], acc[mt][nt], 0, 0, 0);
        #pragma unroll
        for (int nt = 0; nt < 4; ++nt) bx[nt] = *(const short8*)(rb + BL_B + nt * 16 * LDW);
        #pragma unroll
        for (int mt = 0; mt < 4; ++mt)
            #pragma unroll
            for (int nt = 0; nt < 4; ++nt)
                acc[mt][nt] = __builtin_amdgcn_mfma_f32_16x16x32_bf16(ah[mt], bx[nt], acc[mt][nt], 0, 0, 0);
        __syncthreads();
    }

    #pragma unroll
    for (int mt = 0; mt < 4; ++mt) {
        #pragma unroll
        for (int nt = 0; nt < 4; ++nt) {
            const int r0 = m0 + wm * 64 + mt * 16 + quad * 4;
            const int c0 = n0 + wn * 64 + nt * 16 + lr;
            #pragma unroll
            for (int j = 0; j < 4; ++j)
                C[(size_t)(r0 + j) * KC + c0] = acc[mt][nt][j];
        }
    }
}

// ------------------------------------------------------------ block reduce --
__device__ __forceinline__ float block_reduce_sum(float v, volatile float* sf,
                                                  int lane, int w) {
    #pragma unroll
    for (int off = 32; off; off >>= 1) v += __shfl_xor(v, off, 64);
    if (lane == 0) sf[w] = v;
    __syncthreads();
    v = sf[0] + sf[1] + sf[2] + sf[3];
    __syncthreads();
    return v;
}

// ---------------------------------------------------------------- row pass --
// Wave-private rows (r5 structure), 2 rows/wave, 8 rows/block, grid 2048
// (8 blocks/CU at VGPR~64 -> deep latency hiding). NO global atomics for
// diversity: LDS combine + streaming divpart2[b][2048] write (reduced later).
__global__ __launch_bounds__(256) void rowpass(const float* __restrict__ sim,
                                               float* __restrict__ nn,
                                               float* __restrict__ divpart2,  // [2048][2048]
                                               int*   __restrict__ counts,    // ws [2048]
                                               float* __restrict__ entpart,   // ws [2048]
                                               int*   __restrict__ nflag,
                                               int*   __restrict__ flags) {
    __shared__ float divp[KC];
    __shared__ float sent[4];
    const int t = threadIdx.x, lane = t & 63, w = t >> 6;
    const int b = blockIdx.x;
    const int row0 = b * 8 + w * 2;
    const int col0 = lane << 2;

    float4 dacc[8] = {};
    float ent_acc = 0.f;
    const float* base = sim + (size_t)row0 * KC + col0;

    #pragma unroll 1
    for (int rr = 0; rr < 2; ++rr) {
        float4 cur[8];
        const float* rp = base + (size_t)rr * KC;
        #pragma unroll
        for (int j = 0; j < 8; ++j) cur[j] = *(const float4*)(rp + 256 * j);

        // ---- top-2 (value, index), first-occurrence tie rule ----
        float bv = -3.0e38f, rv = -3.0e38f;
        int   bi = 0x7fffffff, ri = 0x7fffffff;
        #pragma unroll
        for (int j = 0; j < 8; ++j) {
            #pragma unroll
            for (int c = 0; c < 4; ++c) {
                float v = (&cur[j].x)[c];
                int   i = col0 + c + 256 * j;
                if (v > bv || (v == bv && i < bi)) { rv = bv; ri = bi; bv = v; bi = i; }
                else if (v > rv || (v == rv && i < ri)) { rv = v; ri = i; }
            }
        }
        #pragma unroll
        for (int off = 32; off; off >>= 1) {
            float obv = __shfl_xor(bv, off, 64);
            int   obi = __shfl_xor(bi, off, 64);
            float orv = __shfl_xor(rv, off, 64);
            int   ori = __shfl_xor(ri, off, 64);
            bool ob = (obv > bv) || (obv == bv && obi < bi);
            float c1v = ob ? bv : obv;  int c1i = ob ? bi : obi;
            float c2v = ob ? orv : rv;  int c2i = ob ? ori : ri;
            bv = ob ? obv : bv;  bi = ob ? obi : bi;
            bool rb = (c1v > c2v) || (c1v == c2v && c1i < c2i);
            rv = rb ? c1v : c2v;  ri = rb ? c1i : c2i;
        }
        const float m = bv;

        // ---- softmax stats: Z = sum e, S = sum e*(s-m) ----
        float Z = 0.f, S = 0.f;
        #pragma unroll
        for (int j = 0; j < 8; ++j) {
            #pragma unroll
            for (int c = 0; c < 4; ++c) {
                float d = (&cur[j].x)[c] - m;
                float e = expf(d);
                Z += e; S += e * d;
                (&cur[j].x)[c] = e;
            }
        }
        #pragma unroll
        for (int off = 32; off; off >>= 1) {
            Z += __shfl_xor(Z, off, 64);
            S += __shfl_xor(S, off, 64);
        }
        const float inv = 1.0f / Z;
        #pragma unroll
        for (int j = 0; j < 8; ++j) {
            dacc[j].x += cur[j].x * inv; dacc[j].y += cur[j].y * inv;
            dacc[j].z += cur[j].z * inv; dacc[j].w += cur[j].w * inv;
        }

        if (lane == 0) {
            // sum p*log2(p+1e-8) = log2e*(S/Z) - log2(Z) + 2048*1e-8*log2e
            ent_acc += 1.4426950408889634f * (S * inv) - log2f(Z) + 2.9546393e-5f;
            atomicAdd(&counts[bi], 1);
            nn[row0 + rr] = (float)bi;
            if (bv - rv < FLAG_TAU) {
                int e = atomicAdd(nflag, 1);
                if (e < FLAG_CAP) {
                    flags[3*e] = row0 + rr; flags[3*e+1] = bi; flags[3*e+2] = ri;
                }
            }
        }
    }

    if (lane == 0) sent[w] = ent_acc;
    // deterministic cross-wave diversity combine in LDS, then streamed write
    for (int ww = 0; ww < 4; ++ww) {
        if (w == ww) {
            #pragma unroll
            for (int j = 0; j < 8; ++j) {
                float4* p = (float4*)&divp[col0 + 256 * j];
                if (ww == 0) *p = dacc[j];
                else {
                    float4 v = *p;
                    v.x += dacc[j].x; v.y += dacc[j].y;
                    v.z += dacc[j].z; v.w += dacc[j].w;
                    *p = v;
                }
            }
        }
        __syncthreads();
    }
    float4* dst = (float4*)(divpart2 + (size_t)b * KC);
    dst[t]       = *(float4*)&divp[t * 4];
    dst[t + 256] = *(float4*)&divp[t * 4 + 1024];
    if (t == 0) entpart[b] = sent[0] + sent[1] + sent[2] + sent[3];
}

// --------------------------------------- redA: partial reduce + fixup -------
// blocks 0..255: part2[b] = sum of divpart2 rows [8b, 8b+8)  (coalesced)
// block 256:     exact fp32 re-check of flagged near-tie rows
__global__ __launch_bounds__(256) void redA(const float* __restrict__ divpart2,
                                            float* __restrict__ part2,       // [256][2048]
                                            const float* __restrict__ A,
                                            const float* __restrict__ B,
                                            float* __restrict__ nn,
                                            int*   __restrict__ counts,
                                            const int* __restrict__ flags,
                                            const int* __restrict__ nflagp) {
    const int t = threadIdx.x;
    if (blockIdx.x < 256) {
        const int b = blockIdx.x;
        const float4* dp = (const float4*)(divpart2 + (size_t)b * 8 * KC);
        float4 s0 = dp[t], s1 = dp[t + 256];
        #pragma unroll
        for (int r = 1; r < 8; ++r) {
            float4 u = dp[(size_t)r * 512 + t];
            float4 v = dp[(size_t)r * 512 + t + 256];
            s0.x += u.x; s0.y += u.y; s0.z += u.z; s0.w += u.w;
            s1.x += v.x; s1.y += v.y; s1.z += v.z; s1.w += v.w;
        }
        float4* o = (float4*)(part2 + (size_t)b * KC);
        o[t] = s0; o[t + 256] = s1;
    } else {
        __shared__ float sf[4];
        const int lane = t & 63, w = t >> 6;
        int nf = *nflagp; if (nf > FLAG_CAP) nf = FLAG_CAP;
        for (int e = 0; e < nf; ++e) {
            const int row = flags[3*e], i1 = flags[3*e+1], i2 = flags[3*e+2];
            const float* ar = A + (size_t)row * DIM;
            const float* b1 = B + (size_t)i1 * DIM;
            const float* b2 = B + (size_t)i2 * DIM;
            float d1 = ar[t] * b1[t] + ar[t + 256] * b1[t + 256];
            float d2 = ar[t] * b2[t] + ar[t + 256] * b2[t + 256];
            d1 = block_reduce_sum(d1, sf, lane, w);
            d2 = block_reduce_sum(d2, sf, lane, w);
            if (t == 0 && (d2 > d1 || (d2 == d1 && i2 < i1))) {
                nn[row] = (float)i2;
                atomicSub(&counts[i1], 1);
                atomicAdd(&counts[i2], 1);
            }
            __syncthreads();
        }
    }
}

// -------------------------------- finB: column totals -> d*log2(d), + Se ----
__global__ __launch_bounds__(256) void finB(const float* __restrict__ part2,
                                            const float* __restrict__ entpart,
                                            float* __restrict__ divlog8,
                                            float* __restrict__ sep) {
    __shared__ float sf[4];
    const int t = threadIdx.x, lane = t & 63, w = t >> 6;
    const int g = blockIdx.x;
    const int c = g * 256 + t;
    float s = 0.f;
    for (int r = 0; r < 256; ++r) s += part2[(size_t)r * KC + c];
    float d = s * (1.0f / 16384.0f);
    float v = d * log2f(d + 1e-8f);
    float S = block_reduce_sum(v, sf, lane, w);
    if (t == 0) divlog8[g] = S;
    if (g == 7) {
        float se = 0.f;
        #pragma unroll
        for (int k = 0; k < 8; ++k) se += entpart[t + 256 * k];
        float Se = block_reduce_sum(se, sf, lane, w);
        if (t == 0) sep[0] = Se;
    }
}

__global__ void fin2(const float* __restrict__ divlog8,
                     const float* __restrict__ sep,
                     float* __restrict__ lossp) {
    if (threadIdx.x == 0) {
        double Sd = 0.0;
        #pragma unroll
        for (int g = 0; g < 8; ++g) Sd += (double)divlog8[g];
        lossp[0] = (float)(-(double)sep[0] / 16384.0 + Sd);
    }
}

// ------------------------------------------------------- quantize+epilogue --
__global__ __launch_bounds__(256) void tail(const float* __restrict__ cb,
                                            const float* __restrict__ oldc,
                                            const int*   __restrict__ counts,
                                            const float* __restrict__ lossp,
                                            const int*   __restrict__ train,
                                            const float* __restrict__ nn,
                                            float* __restrict__ out) {
    const int bb = blockIdx.x;
    const int t  = threadIdx.x;
    if (bb < 4096) {
        // quantize 4 rows/block; STE output == q_norm exactly (x+(q-x)=q)
        const int lane = t & 63;
        const int row  = (bb << 2) + (t >> 6);
        const int idx  = (int)nn[row];
        const float* c = cb + (size_t)idx * DIM;

        float4 q0 = *(const float4*)(c + lane * 8);
        float4 q1 = *(const float4*)(c + lane * 8 + 4);

        float s = q0.x+q0.y+q0.z+q0.w + q1.x+q1.y+q1.z+q1.w;
        #pragma unroll
        for (int off = 32; off; off >>= 1) s += __shfl_xor(s, off, 64);
        const float mean = s * (1.0f / 512.0f);
        q0.x -= mean; q0.y -= mean; q0.z -= mean; q0.w -= mean;
        q1.x -= mean; q1.y -= mean; q1.z -= mean; q1.w -= mean;

        float ss = q0.x*q0.x+q0.y*q0.y+q0.z*q0.z+q0.w*q0.w
                 + q1.x*q1.x+q1.y*q1.y+q1.z*q1.z+q1.w*q1.w;
        #pragma unroll
        for (int off = 32; off; off >>= 1) ss += __shfl_xor(ss, off, 64);
        const float inv = 1.0f / sqrtf(ss);

        float4 o0, o1;
        o0.x = q0.x*inv; o0.y = q0.y*inv; o0.z = q0.z*inv; o0.w = q0.w*inv;
        o1.x = q1.x*inv; o1.y = q1.y*inv; o1.z = q1.z*inv; o1.w = q1.w*inv;
        nt_store4(out + (size_t)row * DIM + lane * 8, o0);
        nt_store4(out + (size_t)row * DIM + lane * 8 + 4, o1);
    } else {
        const size_t LOSS4 = 33554432ul / 4;
        const size_t CB4   = 1048576ul  / 4;
        size_t i = (size_t)(bb - 4096) * 256 + t;
        if (i < LOSS4) {
            const float l = lossp[0];
            nt_store4(out + LOSS_OFF + i * 4, make_float4(l, l, l, l));
        } else if (i < LOSS4 + CB4) {
            size_t j = i - LOSS4;
            nt_store4(out + CB_OFF + j * 4, ((const float4*)cb)[j]);
        } else {
            size_t k = i - LOSS4 - CB4;
            if (k < 2048) {
                float nc = train[0] ? 0.99f * oldc[k] + 0.01f * (float)counts[k]
                                    : oldc[k];
                out[CNT_OFF + k] = nc;
            }
        }
    }
}

// ------------------------------------------------------------------ launch --
extern "C" void kernel_launch(void* const* d_in, const int* in_sizes, int n_in,
                              void* d_out, int out_size, void* d_ws, size_t ws_size,
                              hipStream_t stream) {
    const float* x     = (const float*)d_in[0];
    const float* cb    = (const float*)d_in[1];
    const float* oldc  = (const float*)d_in[2];
    const int*   train = (const int*)d_in[3];
    float* out = (float*)d_out;

    float* sim      = out + LOSS_OFF;  // sim scratch in loss region
    float* divpart2 = out + Q_OFF;     // [2048][2048] in quantized region
    float* part2    = out + CB_OFF;    // [256][2048] in codebook-copy region
    float* nn       = out + NN_OFF;

    float* lossp   = (float*)d_ws + WS_LOSS;
    int*   counts  = (int*)d_ws   + WS_CNT;
    float* entpart = (float*)d_ws + WS_ENT;
    int*   nflag   = (int*)d_ws   + WS_NFLAG;
    int*   flags   = (int*)d_ws   + WS_FLAGS;
    float* divlog8 = (float*)d_ws + WS_DIVLOG;
    float* sep     = (float*)d_ws + WS_SE;

    gemm_mfma<<<dim3(KC / 128, NROWS / 128), 256, 0, stream>>>(x, cb, sim, (int*)d_ws);
    rowpass<<<2048, 256, 0, stream>>>(sim, nn, divpart2, counts, entpart, nflag, flags);
    redA<<<257, 256, 0, stream>>>(divpart2, part2, x, cb, nn, counts, flags, nflag);
    finB<<<8, 256, 0, stream>>>(part2, entpart, divlog8, sep);
    fin2<<<1, 64, 0, stream>>>(divlog8, sep, lossp);
    tail<<<4096 + 33800, 256, 0, stream>>>(cb, oldc, counts, lossp, train, nn, out);
}